// Round 3
// baseline (80.216 us; speedup 1.0000x reference)
//
#include <hip/hip_runtime.h>

#define GRID 256
#define NTHR 256

// ws layout: int ctrl[4] {arrive, ticket, count, pad} | float part[768]
// part[0..255]=wmse partial, part[256..511]=min, part[512..767]=max

__global__ __launch_bounds__(256) void SPL_fused(const float* __restrict__ pred,
                                                 const float* __restrict__ tgt,
                                                 int* __restrict__ ctrl,
                                                 float* __restrict__ part,
                                                 float* __restrict__ out) {
    __shared__ float sP[1280], sT[1280];   // 10 rows x 128 cols, zero-padded
    __shared__ float vsP[256], vsT[256];   // vertical 9-sums
    __shared__ float red[12];
    __shared__ int   ired[4];
    __shared__ int   amLast;

    int b = blockIdx.x;
    int t = threadIdx.x;
    int m  = b >> 6;              // image 0..3
    int r2 = (b & 63) << 1;       // first of this block's 2 output rows
    const float* p = pred + (m << 14);
    const float* q = tgt  + (m << 14);

    // ---- phase 1: separable edge-corrected 9x9 box mean -> dists in regs ----
#pragma unroll
    for (int s = 0; s < 5; ++s) {
        int k   = t + s * 256;    // 0..1279
        int rr  = k >> 7;
        int cc  = k & 127;
        int grw = r2 - 4 + rr;
        bool ok = (unsigned)grw < 128u;
        sP[k] = ok ? p[(grw << 7) + cc] : 0.f;
        sT[k] = ok ? q[(grw << 7) + cc] : 0.f;
    }
    __syncthreads();

    int orow = t >> 7;            // 0/1
    int col  = t & 127;
    int row  = r2 + orow;

    float vp = 0.f, vt = 0.f;
    int vb = orow * 128 + col;
#pragma unroll
    for (int di = 0; di < 9; ++di) {
        vp += sP[vb + di * 128];
        vt += sT[vb + di * 128];
    }
    vsP[t] = vp; vsT[t] = vt;
    __syncthreads();

    float sp = 0.f, st = 0.f;
    int rbase = t & ~127;
#pragma unroll
    for (int dj = -4; dj <= 4; ++dj) {
        int jj = col + dj;
        if ((unsigned)jj < 128u) { sp += vsP[rbase + jj]; st += vsT[rbase + jj]; }
    }

    int   rc  = min(row, 4) + min(127 - row, 4) + 1;
    int   cn  = min(col, 4) + min(127 - col, 4) + 1;
    float den = (float)(rc * cn);
    float pv  = sP[(orow + 4) * 128 + col];
    float tv  = sT[(orow + 4) * 128 + col];
    float pd  = pv - sp / den;    // stays in registers across the barrier
    float td  = tv - st / den;

    // wmse term + block min/max partials
    float w = 1.f;
    if (tv >= 0.5f) w = 2.f;
    if (tv >= 2.f)  w = 5.f;
    if (tv >= 5.f)  w = 10.f;
    if (tv >= 10.f) w = 30.f;
    float d  = pv - tv;
    float s1 = w * d * d;
    float mn = fminf(pd, td);
    float mx = fmaxf(pd, td);

    for (int o = 32; o > 0; o >>= 1) {
        s1 += __shfl_down(s1, o, 64);
        mn  = fminf(mn, __shfl_down(mn, o, 64));
        mx  = fmaxf(mx, __shfl_down(mx, o, 64));
    }
    int lane = t & 63, wid = t >> 6;
    if (lane == 0) { red[wid] = s1; red[4 + wid] = mn; red[8 + wid] = mx; }
    __syncthreads();
    if (t == 0) {
        part[b]       = red[0] + red[1] + red[2] + red[3];
        part[256 + b] = fminf(fminf(red[4], red[5]), fminf(red[6], red[7]));
        part[512 + b] = fmaxf(fmaxf(red[8], red[9]), fmaxf(red[10], red[11]));
    }

    // ---- grid barrier (all 1024 waves co-resident: 256 blocks, ~12KB LDS) ----
    if (t == 0) {
        __threadfence();                           // release partials
        atomicAdd(&ctrl[0], 1);
        while (__hip_atomic_load(&ctrl[0], __ATOMIC_ACQUIRE,
                                 __HIP_MEMORY_SCOPE_AGENT) < GRID) { }
    }
    __syncthreads();

    // ---- phase 2: global lo/hi, analytic grid-point count ----
    float mn2 = part[256 + t];
    float mx2 = part[512 + t];
    for (int o = 32; o > 0; o >>= 1) {
        mn2 = fminf(mn2, __shfl_down(mn2, o, 64));
        mx2 = fmaxf(mx2, __shfl_down(mx2, o, 64));
    }
    if (lane == 0) { red[wid] = mn2; red[4 + wid] = mx2; }
    __syncthreads();
    float lo = fminf(fminf(red[0], red[1]), fminf(red[2], red[3]));
    float hi = fmaxf(fmaxf(red[4], red[5]), fmaxf(red[6], red[7]));
    float dx = (hi - lo) / 999.0f;

    // #{k in [0,1000) : lo + k*dx in [min(pd,td), max(pd,td))}
    float a  = fminf(pd, td);
    float b2 = fmaxf(pd, td);
    int ka = (int)ceilf((a - lo) / dx);
    int kb = (int)ceilf((b2 - lo) / dx);
    ka = max(ka, 0);
    kb = min(kb, 1000);
    int cnt = max(kb - ka, 0);
    for (int o = 32; o > 0; o >>= 1) cnt += __shfl_down(cnt, o, 64);
    if (lane == 0) ired[wid] = cnt;
    __syncthreads();
    if (t == 0) {
        int c = ired[0] + ired[1] + ired[2] + ired[3];
        atomicAdd(&ctrl[2], c);                    // exact int sum, deterministic
        __threadfence();
        int tk = atomicAdd(&ctrl[1], 1);
        amLast = (tk == GRID - 1);
    }
    __syncthreads();

    // ---- last block: final combine ----
    if (amLast) {
        float ws_ = part[t];                       // wmse partials, fixed order
        for (int o = 32; o > 0; o >>= 1) ws_ += __shfl_down(ws_, o, 64);
        if (lane == 0) red[wid] = ws_;
        __syncthreads();
        if (t == 0) {
            float wtot = red[0] + red[1] + red[2] + red[3];
            int   ctot = atomicAdd(&ctrl[2], 0);   // serialized after all count adds
            float  wmse = wtot * (1.0f / 65536.0f);
            double crps = (double)ctot * (double)dx / 65536.0;
            out[0] = 1e-4f * wmse + (float)crps;
        }
    }
}

extern "C" void kernel_launch(void* const* d_in, const int* in_sizes, int n_in,
                              void* d_out, int out_size, void* d_ws, size_t ws_size,
                              hipStream_t stream) {
    const float* pred = (const float*)d_in[0];
    const float* tgt  = (const float*)d_in[1];
    int*   ctrl = (int*)d_ws;
    float* part = (float*)d_ws + 4;
    float* out  = (float*)d_out;

    hipMemsetAsync(ctrl, 0, 16, stream);   // graph-legal memset node
    SPL_fused<<<GRID, NTHR, 0, stream>>>(pred, tgt, ctrl, part, out);
}